// Round 1
// 9779.886 us; speedup vs baseline: 1.2023x; 1.2023x over previous
//
#include <hip/hip_runtime.h>
#include <math.h>

// UKF, one block per trajectory, now 512 threads (8 waves -> 2 waves/SIMD for
// latency hiding; the old 256-thread version ran at 1 wave/SIMD, VALUBusy 13%).
// n=64 states, m=32 obs, T=250 steps, 128 trajectories (128 blocks: structural).
//
// R3 changes vs R2:
//  - 512 threads: every parallel phase re-tiled (FL 2x4, Pn 4x2, Pxz/K 4-col,
//    Pz 2-col, chol-trailing stride 8, M 272 2x4 lower tiles + x_new on wave7).
//  - Barriers 26 -> 17/step:
//      * Cholesky panel-8 -> panel-16 (15 -> 7 barriers; per-element fma order
//        identical, bitwise-equivalent factorization).
//      * P *= 63 (+eps) scale fused into P_new writeback; initial P pre-scaled.
//      * F^T restage hidden under chol panel-0 factorization (waves 1-7 idle
//        there); no dedicated staging phase.
//  - R rows hoisted to 2 registers (constant over t).
// LDS 63,872 B (sPart grown to 8 partials). One block per CU regardless.

#define NTRAJ 128
#define TSTEPS 250
#define NS 64
#define NO 32
#define PS 65    // P row stride: odd -> column access is free 2-way
#define SFS 68   // sigma buffer row stride: mult of 4 -> float4 rows, >= 65.5 for overlays
#define HTS 36   // H^T row stride (row j holds H[:,j]), float4-aligned
#define PXS 33   // Pxz / K / Pzinv-colmajor row stride
#define GJS 65   // Pz / M stride
#define BLK 512

#define DTc 0.02f
#define W_C (0.5f/63.0f)
#define WM0 (-1.0f/63.0f)
#define WC0 (2.0f - 1.0f/63.0f)

__device__ __forceinline__ float tanh_fast(float x) {
  // tanh(x) = 1 - 2/(e^{2x}+1); handles +-inf saturation naturally.
  float e = __expf(2.0f * x);
  return 1.0f - 2.0f / (e + 1.0f);
}

__global__ __launch_bounds__(BLK)
void ukf_main(const float* __restrict__ Xg, const float* __restrict__ Yg,
              const float* __restrict__ Fg, const float* __restrict__ Hg,
              const float* __restrict__ Qg, const float* __restrict__ Rg,
              float* __restrict__ outX, float* __restrict__ outP,
              float* __restrict__ wsPart)
{
  __shared__ __align__(16) float P[NS*PS];      // 16640: P / chol L / Pn / P_new
  __shared__ __align__(16) float sfb[128*SFS];  // 34816: F^T + FL + sigma; overlaid below
  __shared__ __align__(16) float sHT[NS*HTS];   // 9216: H^T, persistent
  __shared__ float sPart[8*NS];                 // 2048: x_pred partials (8 waves)
  __shared__ float sx[NS], sxp[NS], sFx[NS], s0[NS];
  __shared__ float sinn[NO];

  float* Pxz = sfb;                 // [0,    2112): 64 x PXS
  float* Km  = sfb + NS*PXS;        // [2112, 4224): 64 x PXS
  float* Wgj = sfb + 2*NS*PXS;      // [4224, 6304): 32 x GJS (Pz); later Pzinv col-major 32 x PXS
  float* Mb  = sfb + 2*NS*PXS;      // [4224, 8384): 64 x GJS (M lower, after GJ dead)

  const int tid  = threadIdx.x;
  const int lane = tid & 63;
  const int grp  = tid >> 6;
  const int traj = blockIdx.x;

  // R is constant over t: hoist this thread's two Pz-phase entries into regs.
  const int pzm = tid >> 4;          // 0..31
  const int pzn = tid & 15;          // 0..15
  const float rv0 = Rg[pzm*NO + pzn];
  const float rv1 = Rg[pzm*NO + pzn + 16];

  // ---- one-time init: P pre-scaled = 63*(1e-5 I) + 6.3e-7 I, x = 0, stage H^T
  for (int o = tid; o < NS*NS; o += BLK) {
    int i = o >> 6, j = o & 63;
    P[i*PS + j] = (i == j) ? (63e-5f + 6.3e-7f) : 0.f;
  }
  for (int o = tid; o < NO*NS; o += BLK) {
    int m = o >> 6, j = o & 63;
    sHT[j*HTS + m] = Hg[o];
  }
  if (tid < NS) sx[tid] = 0.f;
  float errAcc = 0.f;
  __syncthreads();

  for (int t = 0; t < TSTEPS; ++t) {
    const size_t sbase = (size_t)traj*TSTEPS + t;

    // ---- Cholesky of A = 63*(P+1e-8 I) (P already pre-scaled): panel-16,
    //      7 barriers. Waves 1-7 stage F^T under panel 0 (free).
    for (int pc = 0; pc < NS; pc += 16) {
      if (grp == 0) {
        const int i = lane;
        float pr[16];
        #pragma unroll
        for (int jj = 0; jj < 16; ++jj) pr[jj] = P[i*PS + pc + jj];
        #pragma unroll
        for (int jj = 0; jj < 16; ++jj) {
          const int gc = pc + jj;
          float dv  = __shfl(pr[jj], gc);       // updated diagonal
          float inv = rsqrtf(dv);
          pr[jj] = (i == gc) ? dv * inv : pr[jj] * inv;  // rows i<gc junk (upper) - harmless
          #pragma unroll
          for (int kk = jj + 1; kk < 16; ++kk) {
            float ck = __shfl(pr[jj], pc + kk); // L[pc+kk][gc]
            pr[kk] = fmaf(-pr[jj], ck, pr[kk]);
          }
        }
        #pragma unroll
        for (int jj = 0; jj < 16; ++jj) P[i*PS + pc + jj] = pr[jj];
      } else if (pc == 0) {
        // stage FT[j][i] = F[i][j] into sfb rows 0..63 (dead overlays under it)
        for (int o = tid - 64; o < NS*NS; o += (BLK - 64)) {
          int i = o >> 6, j = o & 63;
          sfb[j*SFS + i] = Fg[o];
        }
      }
      __syncthreads();
      if (pc < NS - 16) {
        // trailing rank-16 update: all 8 waves (upper-junk rows harmless)
        const int i = lane;
        float Li[16];
        #pragma unroll
        for (int jj = 0; jj < 16; ++jj) Li[jj] = P[i*PS + pc + jj];
        for (int k = pc + 16 + grp; k < NS; k += 8) {
          float acc = P[i*PS + k];
          #pragma unroll
          for (int jj = 0; jj < 16; ++jj)
            acc = fmaf(-Li[jj], P[k*PS + pc + jj], acc); // P[k][..] wave-uniform
          P[i*PS + k] = acc;
        }
        __syncthreads();
      }
    }

    // ---- FL = F @ L into sfb rows 64..127 (row 64+c = FL[:,c]); Fx on wave0
    {
      const int c0 = (tid >> 4) << 1;   // 2 cols
      const int j0 = (tid & 15) << 2;   // 4 rows (float4)
      float a00=0.f,a01=0.f,a02=0.f,a03=0.f, a10=0.f,a11=0.f,a12=0.f,a13=0.f;
      #pragma unroll 2
      for (int jj = 0; jj < NS; ++jj) {
        float4 fv = *(const float4*)&sfb[jj*SFS + j0];   // F[j0..j0+3][jj]
        float lv0 = (jj >= c0)     ? P[jj*PS + c0]     : 0.f;  // L[jj][c0]
        float lv1 = (jj >= c0 + 1) ? P[jj*PS + c0 + 1] : 0.f;
        a00 = fmaf(lv0, fv.x, a00); a01 = fmaf(lv0, fv.y, a01);
        a02 = fmaf(lv0, fv.z, a02); a03 = fmaf(lv0, fv.w, a03);
        a10 = fmaf(lv1, fv.x, a10); a11 = fmaf(lv1, fv.y, a11);
        a12 = fmaf(lv1, fv.z, a12); a13 = fmaf(lv1, fv.w, a13);
      }
      float4 w0; w0.x=a00; w0.y=a01; w0.z=a02; w0.w=a03;
      float4 w1; w1.x=a10; w1.y=a11; w1.z=a12; w1.w=a13;
      *(float4*)&sfb[(64 + c0)*SFS + j0]     = w0;
      *(float4*)&sfb[(64 + c0 + 1)*SFS + j0] = w1;
    }
    if (tid < NS) {            // Fx = F @ x (reads FT rows)
      float a2 = 0.f;
      for (int jj = 0; jj < NS; ++jj) a2 = fmaf(sfb[jj*SFS + tid], sx[jj], a2);
      sFx[tid] = a2;
    }
    __syncthreads();

    // ---- sigma points + fused x_pred partials. rows 0..63 plus, 64..127 minus
    {
      const int j = lane;
      float psum = 0.f;
      float xv = sx[j], fxv = sFx[j];
      for (int cc = grp; cc < NS; cc += 8) {
        float flv = sfb[(64+cc)*SFS + j];
        float Lv  = (j >= cc) ? P[j*PS + cc] : 0.f;
        float vp = xv + Lv + DTc * tanh_fast(fxv + flv);
        float vm = xv - Lv + DTc * tanh_fast(fxv - flv);
        sfb[cc*SFS + j]      = vp;
        sfb[(64+cc)*SFS + j] = vm;
        psum += vp + vm;
      }
      sPart[grp*NS + j] = psum;
    }
    if (tid < NS) s0[tid] = sx[tid] + DTc * tanh_fast(sFx[tid]);
    __syncthreads();

    // ---- combine -> x_pred, center deviation
    if (tid < NS) {
      float s = sPart[tid]        + sPart[NS+tid]   + sPart[2*NS+tid] + sPart[3*NS+tid]
              + sPart[4*NS+tid]   + sPart[5*NS+tid] + sPart[6*NS+tid] + sPart[7*NS+tid];
      float xp = fmaf(W_C, s, WM0 * s0[tid]);
      sxp[tid] = xp;
      s0[tid] -= xp;
    }
    __syncthreads();

    // ---- Pn = Wc0*d0 d0^T + c*sum (sf-x)(sf-x)^T -> P  (4x2 tiles, 512 thr)
    {
      const int i0 = (tid >> 5) << 2;   // 4 rows
      const int j0 = (tid & 31) << 1;   // 2 cols
      float acc[4][2];
      #pragma unroll
      for (int a = 0; a < 4; ++a) { acc[a][0] = 0.f; acc[a][1] = 0.f; }
      float xi[4];
      #pragma unroll
      for (int a = 0; a < 4; ++a) xi[a] = sxp[i0+a];
      const float xj0 = sxp[j0], xj1 = sxp[j0+1];
      #pragma unroll 4
      for (int r = 0; r < 128; ++r) {
        float4 av = *(const float4*)&sfb[r*SFS + i0];
        float2 bv = *(const float2*)&sfb[r*SFS + j0];
        float db0 = bv.x - xj0, db1 = bv.y - xj1;
        #pragma unroll
        for (int a = 0; a < 4; ++a) {
          float da = ((const float*)&av)[a] - xi[a];
          acc[a][0] = fmaf(da, db0, acc[a][0]);
          acc[a][1] = fmaf(da, db1, acc[a][1]);
        }
      }
      const float d0j0 = s0[j0], d0j1 = s0[j0+1];
      #pragma unroll
      for (int a = 0; a < 4; ++a) {
        float d0a = WC0 * s0[i0+a];
        P[(i0+a)*PS + j0]     = fmaf(d0a, d0j0, W_C * acc[a][0]);
        P[(i0+a)*PS + j0 + 1] = fmaf(d0a, d0j1, W_C * acc[a][1]);
      }
    }
    __syncthreads();

    // ---- Pxz = Pn @ H^T (64 x 32): 8 waves x 4-col blocks
    {
      const int i = lane;
      const int cb = grp * 4;
      float acc0=0.f, acc1=0.f, acc2=0.f, acc3=0.f;
      for (int jj = 0; jj < NS; ++jj) {
        float pv = P[i*PS + jj];
        float4 h = *(const float4*)&sHT[jj*HTS + cb];
        acc0 = fmaf(pv, h.x, acc0); acc1 = fmaf(pv, h.y, acc1);
        acc2 = fmaf(pv, h.z, acc2); acc3 = fmaf(pv, h.w, acc3);
      }
      Pxz[i*PXS + cb]     = acc0;
      Pxz[i*PXS + cb + 1] = acc1;
      Pxz[i*PXS + cb + 2] = acc2;
      Pxz[i*PXS + cb + 3] = acc3;
    }
    __syncthreads();

    // ---- Pz = H @ Pxz + R (32 x 32) into Wgj; R from hoisted registers
    {
      float a0 = rv0, a1 = rv1;
      for (int i2 = 0; i2 < NS; ++i2) {
        float hv = sHT[i2*HTS + pzm];
        a0 = fmaf(hv, Pxz[i2*PXS + pzn], a0);
        a1 = fmaf(hv, Pxz[i2*PXS + pzn + 16], a1);
      }
      Wgj[pzm*GJS + pzn]      = a0;
      Wgj[pzm*GJS + pzn + 16] = a1;
    }
    __syncthreads();

    // ---- wave0: in-register Gauss-Jordan inverse of Pz (zero barriers)
    //      wave1: innovation; waves 2-7: P += Q
    if (grp == 0) {
      const int c = lane;                 // augmented column [Pz | I]
      float w[NO];
      #pragma unroll
      for (int r = 0; r < NO; ++r)
        w[r] = (c < NO) ? Wgj[r*GJS + c] : ((c - NO == r) ? 1.f : 0.f);
      #pragma unroll
      for (int p = 0; p < NO; ++p) {
        float piv = __shfl(w[p], p);
        float rp  = 1.0f / piv;
        float wp  = w[p] * rp;            // normalized pivot-row element
        #pragma unroll
        for (int r = 0; r < NO; ++r) {
          if (r == p) continue;
          float cr = __shfl(w[r], p);     // column-p value (pre-update)
          w[r] = fmaf(-cr, wp, w[r]);
        }
        w[p] = wp;
      }
      if (c >= NO) {                       // Pzinv col-major: [col][row], stride PXS
        #pragma unroll
        for (int r = 0; r < NO; ++r) Wgj[(c - NO)*PXS + r] = w[r];
      }
    } else if (grp == 1) {
      if (lane < NO) {
        float z = 0.f;
        for (int jj = 0; jj < NS; ++jj) z = fmaf(sHT[jj*HTS + lane], sxp[jj], z);
        sinn[lane] = Yg[sbase*NO + lane] - z;
      }
    } else {
      for (int o = tid - 128; o < NS*NS; o += 6*64) {
        int i = o >> 6, j = o & 63;
        P[i*PS + j] += Qg[o];
      }
    }
    __syncthreads();

    // ---- K = Pxz @ Pzinv (64 x 32): 8 waves x 4-col blocks
    {
      const int i = lane;
      const int cb = grp * 4;
      float acc0=0.f, acc1=0.f, acc2=0.f, acc3=0.f;
      for (int n2 = 0; n2 < NO; ++n2) {
        float pv = Pxz[i*PXS + n2];
        acc0 = fmaf(pv, Wgj[(cb    )*PXS + n2], acc0);  // wave-uniform reads
        acc1 = fmaf(pv, Wgj[(cb + 1)*PXS + n2], acc1);
        acc2 = fmaf(pv, Wgj[(cb + 2)*PXS + n2], acc2);
        acc3 = fmaf(pv, Wgj[(cb + 3)*PXS + n2], acc3);
      }
      Km[i*PXS + cb]     = acc0;
      Km[i*PXS + cb + 1] = acc1;
      Km[i*PXS + cb + 2] = acc2;
      Km[i*PXS + cb + 3] = acc3;
    }
    __syncthreads();

    // ---- M = K @ Pxz^T, lower-triangle 2x4 tiles (272 of them); wave7: x_new
    if (tid < 272) {
      // pair k: tiles [k(k+1), (k+1)(k+2)); first k+1 -> rb=2k, rest -> rb=2k+1
      int k = (int)((sqrtf(4.f*(float)tid + 1.f) - 1.f) * 0.5f);
      while ((k+1)*(k+2) <= tid) ++k;
      while (k*(k+1) > tid) --k;
      const int r0 = tid - k*(k+1);
      const int rb  = (r0 <= k) ? (2*k) : (2*k + 1);
      const int cb2 = (r0 <= k) ? r0 : (r0 - (k + 1));
      const int i0 = rb << 1, j0 = cb2 << 2;
      float acc[2][4];
      #pragma unroll
      for (int b = 0; b < 4; ++b) { acc[0][b] = 0.f; acc[1][b] = 0.f; }
      for (int m = 0; m < NO; ++m) {
        float ka0 = Km[i0*PXS + m];
        float ka1 = Km[(i0+1)*PXS + m];
        #pragma unroll
        for (int b = 0; b < 4; ++b) {
          float pb = Pxz[(j0+b)*PXS + m];
          acc[0][b] = fmaf(ka0, pb, acc[0][b]);
          acc[1][b] = fmaf(ka1, pb, acc[1][b]);
        }
      }
      #pragma unroll
      for (int b = 0; b < 4; ++b) {
        Mb[i0*GJS + j0 + b]     = acc[0][b];
        Mb[(i0+1)*GJS + j0 + b] = acc[1][b];
      }
    } else if (tid >= 448) {
      const int i = tid - 448;
      float xn = sxp[i];
      #pragma unroll 8
      for (int m = 0; m < NO; ++m) xn = fmaf(Km[i*PXS + m], sinn[m], xn);
      sx[i] = xn;
      outX[sbase*NS + i] = xn;
      float dd = xn - Xg[sbase*NS + i];
      errAcc = fmaf(dd, dd, errAcc);
    }
    __syncthreads();

    // ---- P_new = (Pn + Q) - M_sym; write out; fuse next-step scale 63x + eps
    for (int o = tid; o < NS*NS; o += BLK) {
      int i = o >> 6, j = o & 63;
      float mv = (i >= j) ? Mb[i*GJS + j] : Mb[j*GJS + i];
      float v = P[i*PS + j] - mv;
      outP[sbase*(size_t)(NS*NS) + o] = v;
      float nv = v * 63.f;
      if (i == j) nv += 6.3e-7f;
      P[i*PS + j] = nv;
    }
    __syncthreads();
  }

  // ---- per-trajectory squared-error total (all err lives on wave7)
  if (grp == 7) {
    float v = errAcc;
    for (int off = 32; off > 0; off >>= 1) v += __shfl_down(v, off);
    if (lane == 0) wsPart[traj] = v;
  }
}

__global__ __launch_bounds__(128)
void mse_reduce(const float* __restrict__ part, float* __restrict__ outS)
{
  __shared__ float sbuf[128];
  int tid = threadIdx.x;
  sbuf[tid] = part[tid];
  __syncthreads();
  if (tid < 64) {
    float v = sbuf[tid] + sbuf[tid + 64];
    for (int off = 32; off > 0; off >>= 1) v += __shfl_down(v, off);
    if (tid == 0) {
      float m = v / (128.f * 250.f * 64.f);
      outS[0] = m;
      outS[1] = 10.f * log10f(m);
    }
  }
}

extern "C" void kernel_launch(void* const* d_in, const int* in_sizes, int n_in,
                              void* d_out, int out_size, void* d_ws, size_t ws_size,
                              hipStream_t stream) {
  const float* Xg = (const float*)d_in[0];
  const float* Yg = (const float*)d_in[1];
  const float* Fg = (const float*)d_in[2];
  const float* Hg = (const float*)d_in[3];
  const float* Qg = (const float*)d_in[4];
  const float* Rg = (const float*)d_in[5];

  float* outX = (float*)d_out;                                   // 128*250*64
  float* outP = outX + (size_t)NTRAJ*TSTEPS*NS;                  // 128*250*64*64
  float* outS = outP + (size_t)NTRAJ*TSTEPS*NS*NS;               // 2 scalars
  float* wsP  = (float*)d_ws;                                    // 128 partials

  hipLaunchKernelGGL(ukf_main, dim3(NTRAJ), dim3(BLK), 0, stream,
                     Xg, Yg, Fg, Hg, Qg, Rg, outX, outP, wsP);
  hipLaunchKernelGGL(mse_reduce, dim3(1), dim3(128), 0, stream, wsP, outS);
}